// Round 2
// baseline (47.208 us; speedup 1.0000x reference)
//
#include <hip/hip_runtime.h>

#define K 3

// Knot value at index j, computed on the fly from x (matches the reference's
// fitpack knots: head/tail repeats of x[0]/x[N-1], interior 3-point averages).
__device__ __forceinline__ float tfun(const float* __restrict__ x, int j, int N) {
    if (j <= K) return x[0];
    if (j >= N) return x[N - 1];
    return (x[j - 3] + x[j - 2] + x[j - 1]) / 3.0f;
}

// K1: write output knots; per-point binary search + windowed Cox-de Boor with
// safe_div (0-den -> 0) semantics; store 4 nonzero basis vals + interval index.
__global__ void k1_basis(const float* __restrict__ x, float* __restrict__ out_knots,
                         float* __restrict__ vals, int* __restrict__ j0arr, int N) {
    int i = blockIdx.x * blockDim.x + threadIdx.x;
    if (i >= N) return;
    int nk = N + K + 1;

    out_knots[i] = tfun(x, i, N);
    if (i < nk - N) out_knots[N + i] = x[N - 1];

    float xi = x[i];
    // first index with t(j) > xi, minus 1
    int lo = 0, hi = nk;
    while (lo < hi) { int mid = (lo + hi) >> 1; if (tfun(x, mid, N) <= xi) lo = mid + 1; else hi = mid; }
    int j0 = lo - 1;
    if (j0 > N - 1) j0 = N - 1;   // x >= t[-2] override -> last basis column
    if (j0 < K) j0 = K;
    int c0 = j0 - K;

    float b[K + 2];
    #pragma unroll
    for (int w = 0; w < K + 2; ++w) b[w] = 0.f;
    b[K] = 1.f;

    #pragma unroll
    for (int d = 1; d <= K; ++d) {
        float nb[K + 1];
        #pragma unroll
        for (int w = 0; w <= K; ++w) {
            int j = c0 + w;
            float tj   = tfun(x, j, N);
            float tjd  = tfun(x, j + d, N);
            float tj1  = tfun(x, j + 1, N);
            float tjd1 = tfun(x, j + d + 1, N);
            float denL = tjd - tj;
            float L = (denL == 0.f) ? 0.f : (xi - tj) / denL;
            float denR = tjd1 - tj1;
            float R = (denR == 0.f) ? 0.f : (tjd1 - xi) / denR;
            nb[w] = L * b[w] + R * b[w + 1];
        }
        #pragma unroll
        for (int w = 0; w <= K; ++w) b[w] = nb[w];
    }

    j0arr[i] = j0;
    *(float4*)(vals + i * 4) = make_float4(b[0], b[1], b[2], b[3]);
}

// K2: full 7-wide band of B^T B per column ci (offsets -3..3), +s on diagonal.
// Rows containing column ci are the contiguous j0-range [ci, ci+K].
__global__ void k2_band(const float* __restrict__ vals, const int* __restrict__ j0arr,
                        const float* __restrict__ s_ptr, float* __restrict__ band, int N) {
    int ci = blockIdx.x * blockDim.x + threadIdx.x;
    if (ci >= N) return;

    int lo = 0, hi = N;
    while (lo < hi) { int mid = (lo + hi) >> 1; if (j0arr[mid] < ci) lo = mid + 1; else hi = mid; }
    int rlo = lo;
    hi = N; int tgt = ci + K + 1;
    while (lo < hi) { int mid = (lo + hi) >> 1; if (j0arr[mid] < tgt) lo = mid + 1; else hi = mid; }
    int rhi = lo;

    float acc[2 * K + 1];
    #pragma unroll
    for (int a = 0; a < 2 * K + 1; ++a) acc[a] = 0.f;

    for (int r = rlo; r < rhi; ++r) {
        int wi = ci - (j0arr[r] - K);                    // in [0, K]
        float4 v4 = *(const float4*)(vals + r * 4);
        float v = (wi == 0) ? v4.x : (wi == 1) ? v4.y : (wi == 2) ? v4.z : v4.w;
        #pragma unroll
        for (int o = -K; o <= K; ++o) {
            int wj = wi + o;                             // runtime, but acc idx is static
            float w = (wj == 0) ? v4.x : (wj == 1) ? v4.y : (wj == 2) ? v4.z
                    : (wj == 3) ? v4.w : 0.f;
            acc[o + K] += v * w;
        }
    }
    acc[K] += *s_ptr;

    *(float4*)(band + ci * 8)     = make_float4(acc[0], acc[1], acc[2], acc[3]);
    *(float4*)(band + ci * 8 + 4) = make_float4(acc[4], acc[5], acc[6], 0.f);
}

// K3: single-pass writer. One block per output row (4096 B rows then 4096 BTB
// rows); coalesced float4 stores, zeros except the window float4s.
__global__ __launch_bounds__(256) void k3_write(const float* __restrict__ vals,
                                                const int* __restrict__ j0arr,
                                                const float* __restrict__ band,
                                                float* __restrict__ outB,
                                                float* __restrict__ outBTB, int N) {
    int bid = blockIdx.x;
    int tid = threadIdx.x;
    int fpr = N >> 2;   // float4 per row

    if (bid < N) {
        int i = bid;
        int c0 = j0arr[i] - K;
        float4 v4 = *(const float4*)(vals + i * 4);
        float4* rowp = (float4*)(outB + (long long)i * N);
        int fw0 = c0 >> 2, fw1 = (c0 + K) >> 2;
        for (int f = tid; f < fpr; f += 256) {
            float4 z = make_float4(0.f, 0.f, 0.f, 0.f);
            if (f == fw0 || f == fw1) {
                int e0 = f * 4;
                float e[4];
                #pragma unroll
                for (int l = 0; l < 4; ++l) {
                    int d = e0 + l - c0;
                    e[l] = (d == 0) ? v4.x : (d == 1) ? v4.y : (d == 2) ? v4.z
                         : (d == 3) ? v4.w : 0.f;
                }
                z = make_float4(e[0], e[1], e[2], e[3]);
            }
            rowp[f] = z;
        }
    } else {
        int ci = bid - N;
        float4 b0 = *(const float4*)(band + ci * 8);       // offsets -3..0
        float4 b1 = *(const float4*)(band + ci * 8 + 4);   // offsets  1..3
        float4* rowp = (float4*)(outBTB + (long long)ci * N);
        int wlo = ci - K; if (wlo < 0) wlo = 0;
        int whi = ci + K; if (whi > N - 1) whi = N - 1;
        int fw0 = wlo >> 2, fw1 = whi >> 2;
        for (int f = tid; f < fpr; f += 256) {
            float4 z = make_float4(0.f, 0.f, 0.f, 0.f);
            if (f >= fw0 && f <= fw1) {
                int e0 = f * 4;
                float e[4];
                #pragma unroll
                for (int l = 0; l < 4; ++l) {
                    int d = e0 + l - ci;   // diagonal offset, want [-3, 3]
                    e[l] = (d == -3) ? b0.x : (d == -2) ? b0.y : (d == -1) ? b0.z
                         : (d ==  0) ? b0.w : (d ==  1) ? b1.x : (d ==  2) ? b1.y
                         : (d ==  3) ? b1.z : 0.f;
                }
                z = make_float4(e[0], e[1], e[2], e[3]);
            }
            rowp[f] = z;
        }
    }
}

extern "C" void kernel_launch(void* const* d_in, const int* in_sizes, int n_in,
                              void* d_out, int out_size, void* d_ws, size_t ws_size,
                              hipStream_t stream) {
    const float* x = (const float*)d_in[0];
    const float* s = (const float*)d_in[1];
    int N = in_sizes[0];            // 4096
    int nk = N + K + 1;             // 4100

    float* out = (float*)d_out;
    float* out_knots = out;
    float* out_B = out + nk;                       // 16400 bytes in -> 16B aligned
    float* out_BTB = out_B + (long long)N * N;

    // workspace: band (N*8 f) | vals (N*4 f) | j0 (N i)  ~ 208 KB
    float* band_ws = (float*)d_ws;
    float* vals_ws = band_ws + (long long)N * 8;
    int* j0_ws = (int*)(vals_ws + (long long)N * 4);

    int tb = 256;
    k1_basis<<<(N + tb - 1) / tb, tb, 0, stream>>>(x, out_knots, vals_ws, j0_ws, N);
    k2_band<<<(N + tb - 1) / tb, tb, 0, stream>>>(vals_ws, j0_ws, s, band_ws, N);
    k3_write<<<2 * N, tb, 0, stream>>>(vals_ws, j0_ws, band_ws, out_B, out_BTB, N);
}